// Round 9
// baseline (303.649 us; speedup 1.0000x reference)
//
#include <hip/hip_runtime.h>
#include <math.h>

#define BB 8
#define SS 2048
#define SSG 2050          // SS + 2 guard rows per batch for conv halo
#define DDIM 512
#define KC 1536
#define EPSV 1e-6f
#define SCALE 0.044194173824159216f     // 1/sqrt(512)
#define SCALE2 0.0637586814603857f      // SCALE * log2(e) -> exp(x*SCALE) = exp2(x*SCALE2)

typedef unsigned short ushort_t;
using short8 = __attribute__((ext_vector_type(8))) short;
using f32x4  = __attribute__((ext_vector_type(4))) float;

__device__ inline unsigned short f2bf(float f) {
    union { float f; unsigned int u; } v; v.f = f;
    unsigned int r = v.u + 0x7FFFu + ((v.u >> 16) & 1u);   // RNE
    return (unsigned short)(r >> 16);
}
__device__ inline unsigned int packbf(float a, float b) {
    return (unsigned int)f2bf(a) | ((unsigned int)f2bf(b) << 16);
}
__device__ inline float bf2f(unsigned short s) {
    union { unsigned int u; float f; } v; v.u = ((unsigned int)s) << 16; return v.f;
}

// async global->LDS, 16B/lane; LDS dest is wave-uniform base + lane*16 (linear).
__device__ inline void gload16(const ushort_t* g, ushort_t* l) {
    __builtin_amdgcn_global_load_lds(
        (__attribute__((address_space(1))) const void*)g,
        (__attribute__((address_space(3))) void*)l, 16, 0, 0);
}

// swizzled fragment read from a linear [128][64] bf16 tile (128B rows).
// logical 16B chunk c (0..7) of row -> stored at chunk c ^ (row&7); source applies
// the same XOR (rule #21). R1 measured: SQ_LDS_BANK_CONFLICT == 0 with this pair.
__device__ inline short8 ldswz(const ushort_t* s, int row, int c) {
    return *reinterpret_cast<const short8*>(&s[(row << 6) + ((c ^ (row & 7)) << 3)]);
}

// ---------- kprep: weights->bf16 (pre_g folded) + rope table + x->bf16 + xsum ----------
// blocks [0, 3072): weight cast (+ rope rows for blk < 256)
// blocks [3072, 4096): x cast (guarded layout) + xsum
__global__ __launch_bounds__(256) void kprep(
    const float* __restrict__ x,
    const float* __restrict__ conv_w, const float* __restrict__ Wq,
    const float* __restrict__ Wk, const float* __restrict__ Wv,
    const float* __restrict__ pre_g,
    ushort_t* __restrict__ xbf, float* __restrict__ xsum,
    ushort_t* __restrict__ wcat, ushort_t* __restrict__ wqkv,
    float* __restrict__ rope)
{
    const int blk = blockIdx.x;
    const int t = threadIdx.x;
    if (blk < DDIM * KC / 256) {
        int idx = blk * 256 + t;   // < 512*1536
        {
            int o = idx / KC, kk = idx - o * KC;
            int tp = kk >> 9, i = kk & 511;
            wcat[idx] = f2bf(conv_w[(size_t)o * KC + i * 3 + tp]);
        }
        {
            int n = idx >> 9, d = idx & 511;
            const float* src = (n < 512) ? &Wq[(size_t)n * DDIM + d]
                             : (n < 1024) ? &Wk[(size_t)(n - 512) * DDIM + d]
                             : &Wv[(size_t)(n - 1024) * DDIM + d];
            wqkv[idx] = f2bf(*src * pre_g[d]);      // fold pre_g into W columns
        }
        if (blk < SS / 8) {   // rope table: 8 rows per block
            const int r0 = blk * 8;
            const float invf = (float)pow(10000.0, -(double)(2 * t) / (double)DDIM);
            for (int r = 0; r < 8; r++) {
                int srow = r0 + r;
                float sn, cs;
                sincosf((float)srow * invf, &sn, &cs);
                *reinterpret_cast<float2*>(&rope[((size_t)srow << 9) + 2 * t]) = make_float2(cs, sn);
            }
        }
    } else {
        const int i  = blk - DDIM * KC / 256;   // 0..1023
        const int b  = i >> 7;
        const int r0 = (i & 127) * 16;
        const int rg = t >> 7;                   // 0..1 (row group)
        const int c0 = (t & 127) * 4;            // 4 cols per thread
        if ((i & 127) == 0 && rg == 0) {         // zero guard rows
            *reinterpret_cast<uint2*>(&xbf[((size_t)b * SSG) * DDIM + c0]) = make_uint2(0u, 0u);
            *reinterpret_cast<uint2*>(&xbf[((size_t)b * SSG + SS + 1) * DDIM + c0]) = make_uint2(0u, 0u);
        }
        float s0 = 0.f, s1 = 0.f, s2 = 0.f, s3 = 0.f;
        for (int r = 0; r < 8; r++) {
            size_t srow = (size_t)b * SS + r0 + rg * 8 + r;
            size_t drow = (size_t)b * SSG + 1 + r0 + rg * 8 + r;
            float4 v = *reinterpret_cast<const float4*>(&x[srow * DDIM + c0]);
            s0 += v.x; s1 += v.y; s2 += v.z; s3 += v.w;
            uint2 pk;
            pk.x = packbf(v.x, v.y);
            pk.y = packbf(v.z, v.w);
            *reinterpret_cast<uint2*>(&xbf[drow * DDIM + c0]) = pk;
        }
        atomicAdd(&xsum[b * DDIM + c0],     s0);
        atomicAdd(&xsum[b * DDIM + c0 + 1], s1);
        atomicAdd(&xsum[b * DDIM + c0 + 2], s2);
        atomicAdd(&xsum[b * DDIM + c0 + 3], s3);
    }
}

// ---------- shared GEMM inner compute (one BK=64 tile) — R1-verified ----------
#define COMPUTE_TILE(Acur, Bcur) do { \
    _Pragma("unroll") \
    for (int half = 0; half < 2; half++) { \
        const int cb = (half << 2) | lq; \
        short8 af0 = ldswz(Acur, wm * 64 +  0 + lm, cb); \
        short8 af1 = ldswz(Acur, wm * 64 + 16 + lm, cb); \
        short8 af2 = ldswz(Acur, wm * 64 + 32 + lm, cb); \
        short8 af3 = ldswz(Acur, wm * 64 + 48 + lm, cb); \
        _Pragma("unroll") \
        for (int nt = 0; nt < 4; nt++) { \
            short8 bfv = ldswz(Bcur, wn * 64 + nt * 16 + lm, cb); \
            acc[0][nt] = __builtin_amdgcn_mfma_f32_16x16x32_bf16(af0, bfv, acc[0][nt], 0, 0, 0); \
            acc[1][nt] = __builtin_amdgcn_mfma_f32_16x16x32_bf16(af1, bfv, acc[1][nt], 0, 0, 0); \
            acc[2][nt] = __builtin_amdgcn_mfma_f32_16x16x32_bf16(af2, bfv, acc[2][nt], 0, 0, 0); \
            acc[3][nt] = __builtin_amdgcn_mfma_f32_16x16x32_bf16(af3, bfv, acc[3][nt], 0, 0, 0); \
        } \
    } } while (0)

// ---------- k1b: conv GEMM, BK=64, R1 loop; batch-affine grid ----------
__global__ __launch_bounds__(256) void k1b_conv(
    const ushort_t* __restrict__ xbf, const ushort_t* __restrict__ wcat,
    const float* __restrict__ conv_b, ushort_t* __restrict__ ybf, float* __restrict__ rs)
{
    __shared__ alignas(16) ushort_t As[128 * 64];
    __shared__ alignas(16) ushort_t Bs[128 * 64];
    const int t = threadIdx.x;
    const int lane = t & 63, w = t >> 6;
    const int lm = lane & 15, lq = lane >> 4;
    const int wm = w >> 1, wn = w & 1;
    const int lr = lane >> 3;                 // row within 8-row load block
    const int lc = ((lane & 7) ^ lr) << 3;    // source-side XOR-swizzled chunk
    const int b  = blockIdx.x;
    const int s0 = blockIdx.y * 128;
    const int n0 = blockIdx.z * 128;
    const ushort_t* Ag = xbf + (size_t)b * SSG * DDIM;   // guard base: g-row = true + 1
    const ushort_t* Bg = wcat + (size_t)n0 * KC;

    const ushort_t* pa[4]; const ushort_t* pb[4];
    int la[4];
    #pragma unroll
    for (int i = 0; i < 4; i++) {
        const int tr = (w * 4 + i) * 8 + lr;
        pa[i] = &Ag[(size_t)(s0 + tr) * DDIM + lc];
        pb[i] = &Bg[(size_t)tr * KC + lc];
        la[i] = (w * 4 + i) * 512;
    }

    f32x4 acc[4][4];
    #pragma unroll
    for (int i = 0; i < 4; i++)
        #pragma unroll
        for (int j = 0; j < 4; j++) acc[i][j] = (f32x4){0.f, 0.f, 0.f, 0.f};

    for (int dc = 0; dc < 24; dc++) {
        __syncthreads();                       // prev tile reads done
        const int koff = dc * 64;              // tap*512 + kblk*64 == dc*64 (uniform)
        #pragma unroll
        for (int i = 0; i < 4; i++) {
            gload16(pa[i] + koff, &As[la[i]]);
            gload16(pb[i] + koff, &Bs[la[i]]);
        }
        __syncthreads();                       // vmcnt(0) drain -> tile ready
        COMPUTE_TILE(As, Bs);
    }

    const int rbase = s0 + wm * 64;
    const int cbase = n0 + wn * 64;
    ushort_t* yb = ybf + (size_t)b * SS * DDIM;
    float* rsb = rs + (size_t)b * SS;
    float bias[4];
    #pragma unroll
    for (int nt = 0; nt < 4; nt++) bias[nt] = conv_b[cbase + nt * 16 + lm];
    #pragma unroll
    for (int mt = 0; mt < 4; mt++) {
        float pr[4] = {0.f, 0.f, 0.f, 0.f};
        #pragma unroll
        for (int nt = 0; nt < 4; nt++) {
            #pragma unroll
            for (int r = 0; r < 4; r++) {
                float val = acc[mt][nt][r] + bias[nt];
                yb[(size_t)(rbase + mt * 16 + lq * 4 + r) * DDIM + cbase + nt * 16 + lm] = f2bf(val);
                pr[r] = fmaf(val, val, pr[r]);
            }
        }
        #pragma unroll
        for (int r = 0; r < 4; r++) {
            float p = pr[r];
            p += __shfl_xor(p, 1, 64); p += __shfl_xor(p, 2, 64);
            p += __shfl_xor(p, 4, 64); p += __shfl_xor(p, 8, 64);
            if (lm == 0) atomicAdd(&rsb[rbase + mt * 16 + lq * 4 + r], p);
        }
    }
}

// ---------- k1c: QKV GEMM from ybf (pre_g folded into W), inv[s] applied in epilogue ----------
__global__ __launch_bounds__(256) void k1c_qkv(
    const ushort_t* __restrict__ ybf, const float* __restrict__ rs,
    const ushort_t* __restrict__ wqkv,
    ushort_t* __restrict__ qraw, ushort_t* __restrict__ kraw, ushort_t* __restrict__ vb,
    float* __restrict__ rq, float* __restrict__ rk)
{
    __shared__ alignas(16) ushort_t As[128 * 64];
    __shared__ alignas(16) ushort_t Bs[128 * 64];
    const int t = threadIdx.x;
    const int lane = t & 63, w = t >> 6;
    const int lm = lane & 15, lq = lane >> 4;
    const int wm = w >> 1, wn = w & 1;
    const int lr = lane >> 3;
    const int lc = ((lane & 7) ^ lr) << 3;
    const int b  = blockIdx.x;
    const int s0 = blockIdx.y * 128;
    const int nt9 = blockIdx.z;                 // 0..11: which*4 + coltile
    const int n0 = nt9 * 128;
    const ushort_t* Ag = ybf + ((size_t)b * SS + s0) * DDIM;
    const ushort_t* Bg = wqkv + (size_t)n0 * DDIM;

    const ushort_t* pa[4]; const ushort_t* pb[4];
    int la[4];
    #pragma unroll
    for (int i = 0; i < 4; i++) {
        const int tr = (w * 4 + i) * 8 + lr;
        pa[i] = &Ag[(size_t)tr * DDIM + lc];
        pb[i] = &Bg[(size_t)tr * DDIM + lc];
        la[i] = (w * 4 + i) * 512;
    }

    f32x4 acc[4][4];
    #pragma unroll
    for (int i = 0; i < 4; i++)
        #pragma unroll
        for (int j = 0; j < 4; j++) acc[i][j] = (f32x4){0.f, 0.f, 0.f, 0.f};

    for (int dc = 0; dc < 8; dc++) {
        __syncthreads();
        const int koff = dc * 64;
        #pragma unroll
        for (int i = 0; i < 4; i++) {
            gload16(pa[i] + koff, &As[la[i]]);
            gload16(pb[i] + koff, &Bs[la[i]]);
        }
        __syncthreads();
        COMPUTE_TILE(As, Bs);
    }

    const int which = nt9 >> 2;              // 0=q 1=k 2=v
    const int rbase = s0 + wm * 64;
    const int cbase = ((nt9 & 3) * 128) + wn * 64;
    const float* rsb = rs + (size_t)b * SS;
    float inv[4][4];                          // per-row rmsnorm inverse (pre-norm)
    #pragma unroll
    for (int mt = 0; mt < 4; mt++)
        #pragma unroll
        for (int r = 0; r < 4; r++)
            inv[mt][r] = rsqrtf(rsb[rbase + mt * 16 + lq * 4 + r] * (1.0f / DDIM) + EPSV);

    if (which == 2) {
        ushort_t* vbb = vb + (size_t)b * SS * DDIM;
        #pragma unroll
        for (int mt = 0; mt < 4; mt++)
            #pragma unroll
            for (int nt = 0; nt < 4; nt++)
                #pragma unroll
                for (int r = 0; r < 4; r++)
                    vbb[(size_t)(rbase + mt * 16 + lq * 4 + r) * DDIM + cbase + nt * 16 + lm] =
                        f2bf(acc[mt][nt][r] * inv[mt][r]);
    } else {
        ushort_t* db2 = (which ? kraw : qraw) + (size_t)b * SS * DDIM;
        float* rb = (which ? rk : rq) + (size_t)b * SS;
        #pragma unroll
        for (int mt = 0; mt < 4; mt++) {
            float pr[4] = {0.f, 0.f, 0.f, 0.f};
            #pragma unroll
            for (int nt = 0; nt < 4; nt++) {
                #pragma unroll
                for (int r = 0; r < 4; r++) {
                    float val = acc[mt][nt][r] * inv[mt][r];
                    db2[(size_t)(rbase + mt * 16 + lq * 4 + r) * DDIM + cbase + nt * 16 + lm] = f2bf(val);
                    pr[r] = fmaf(val, val, pr[r]);
                }
            }
            #pragma unroll
            for (int r = 0; r < 4; r++) {
                float p = pr[r];
                p += __shfl_xor(p, 1, 64); p += __shfl_xor(p, 2, 64);
                p += __shfl_xor(p, 4, 64); p += __shfl_xor(p, 8, 64);
                if (lm == 0) atomicAdd(&rb[rbase + mt * 16 + lq * 4 + r], p);
            }
        }
    }
}

// ---------- k1d: rmsnorm(q,k) + rope (table), in-place; vectorized 8 bf16/thread ----------
__global__ __launch_bounds__(256) void k1d_rope(
    ushort_t* q_io, ushort_t* k_io,
    const float* __restrict__ rq, const float* __restrict__ rk,
    const float* __restrict__ q_g, const float* __restrict__ k_g,
    const float* __restrict__ rope)
{
    const int t = threadIdx.x;
    const int b = blockIdx.x;
    const int r0 = blockIdx.y * 8;
    const int tr = t >> 6;                    // 0..3
    const int c0 = (t & 63) * 8;              // 8 cols per thread
    float4 qg0 = *reinterpret_cast<const float4*>(&q_g[c0]);
    float4 qg1 = *reinterpret_cast<const float4*>(&q_g[c0 + 4]);
    float4 kg0 = *reinterpret_cast<const float4*>(&k_g[c0]);
    float4 kg1 = *reinterpret_cast<const float4*>(&k_g[c0 + 4]);
    const float qg[8] = {qg0.x, qg0.y, qg0.z, qg0.w, qg1.x, qg1.y, qg1.z, qg1.w};
    const float kg[8] = {kg0.x, kg0.y, kg0.z, kg0.w, kg1.x, kg1.y, kg1.z, kg1.w};
    #pragma unroll
    for (int r = 0; r < 2; r++) {
        const int srow = r0 + tr + 4 * r;
        const size_t rowi = (size_t)b * SS + srow;
        const float iq = rsqrtf(rq[rowi] * (1.0f / DDIM) + EPSV);
        const float ik = rsqrtf(rk[rowi] * (1.0f / DDIM) + EPSV);
        const size_t off = rowi * DDIM + c0;
        uint4 qv = *reinterpret_cast<const uint4*>(&q_io[off]);
        uint4 kv = *reinterpret_cast<const uint4*>(&k_io[off]);
        float4 cs0 = *reinterpret_cast<const float4*>(&rope[((size_t)srow << 9) + c0]);
        float4 cs1 = *reinterpret_cast<const float4*>(&rope[((size_t)srow << 9) + c0 + 4]);
        const float cs[4] = {cs0.x, cs0.z, cs1.x, cs1.z};
        const float sn[4] = {cs0.y, cs0.w, cs1.y, cs1.w};
        unsigned int qw[4] = {qv.x, qv.y, qv.z, qv.w};
        unsigned int kw[4] = {kv.x, kv.y, kv.z, kv.w};
        uint4 qo, ko;
        unsigned int* qop = &qo.x; unsigned int* kop = &ko.x;
        #pragma unroll
        for (int j = 0; j < 4; j++) {
            float qa = bf2f((ushort_t)(qw[j] & 0xFFFF)) * iq * qg[2 * j];
            float qb = bf2f((ushort_t)(qw[j] >> 16))    * iq * qg[2 * j + 1];
            float ka = bf2f((ushort_t)(kw[j] & 0xFFFF)) * ik * kg[2 * j];
            float kb = bf2f((ushort_t)(kw[j] >> 16))    * ik * kg[2 * j + 1];
            qop[j] = packbf(qa * cs[j] - qb * sn[j], qa * sn[j] + qb * cs[j]);
            kop[j] = packbf(ka * cs[j] - kb * sn[j], ka * sn[j] + kb * cs[j]);
        }
        *reinterpret_cast<uint4*>(&q_io[off]) = qo;
        *reinterpret_cast<uint4*>(&k_io[off]) = ko;
    }
}

// ---------- k2a: scores GEMM (R1 loop, unchanged) -> P + row sums l ----------
// Grid (BB, qt, kt): linear id % 8 == batch -> XCD-affine; per-batch Q+K (4MB) ~fits one L2.
__global__ __launch_bounds__(256) void k2a_rowsum(
    const ushort_t* __restrict__ qb, const ushort_t* __restrict__ kb,
    ushort_t* __restrict__ P, float* __restrict__ l)
{
    __shared__ alignas(16) ushort_t As[128 * 64];
    __shared__ alignas(16) ushort_t Bs[128 * 64];
    const int t = threadIdx.x;
    const int lane = t & 63, w = t >> 6;
    const int lm = lane & 15, lq = lane >> 4;
    const int wm = w >> 1, wn = w & 1;
    const int lr = lane >> 3;
    const int lc = ((lane & 7) ^ lr) << 3;
    const int b  = blockIdx.x;
    const int qt = blockIdx.y;
    const int kt = blockIdx.z;
    const ushort_t* Ag = qb + ((size_t)b * SS + qt * 128) * DDIM;
    const ushort_t* Bg = kb + ((size_t)b * SS + kt * 128) * DDIM;

    const ushort_t* pa[4]; const ushort_t* pb[4];
    int la[4];
    #pragma unroll
    for (int i = 0; i < 4; i++) {
        const int tr = (w * 4 + i) * 8 + lr;
        pa[i] = &Ag[(size_t)tr * DDIM + lc];
        pb[i] = &Bg[(size_t)tr * DDIM + lc];
        la[i] = (w * 4 + i) * 512;
    }

    f32x4 acc[4][4];
    #pragma unroll
    for (int i = 0; i < 4; i++)
        #pragma unroll
        for (int j = 0; j < 4; j++) acc[i][j] = (f32x4){0.f, 0.f, 0.f, 0.f};

    for (int dc = 0; dc < 8; dc++) {
        __syncthreads();
        const int koff = dc * 64;
        #pragma unroll
        for (int i = 0; i < 4; i++) {
            gload16(pa[i] + koff, &As[la[i]]);
            gload16(pb[i] + koff, &Bs[la[i]]);
        }
        __syncthreads();
        COMPUTE_TILE(As, Bs);
    }

    const int rbase = qt * 128 + wm * 64;
    const int cbase = kt * 128 + wn * 64;
    ushort_t* Pb = P + (size_t)b * SS * SS;
    float* lrow = l + (size_t)b * SS;
    #pragma unroll
    for (int mt = 0; mt < 4; mt++) {
        #pragma unroll
        for (int r = 0; r < 4; r++) {
            const int row = rbase + mt * 16 + lq * 4 + r;
            float rowp = 0.f;
            #pragma unroll
            for (int nt = 0; nt < 4; nt++) {
                float e = exp2f(acc[mt][nt][r] * SCALE2);
                Pb[(size_t)row * SS + cbase + nt * 16 + lm] = f2bf(e);
                rowp += e;
            }
            float p = rowp;
            p += __shfl_xor(p, 1, 64); p += __shfl_xor(p, 2, 64);
            p += __shfl_xor(p, 4, 64); p += __shfl_xor(p, 8, 64);
            if (lm == 0) atomicAdd(&lrow[row], p);
        }
    }
}

// ---------- k2c: cw[k] = sum_q P[q][k] / l[q] ----------
__global__ __launch_bounds__(256) void k2c_colred(
    const ushort_t* __restrict__ P, const float* __restrict__ l,
    float* __restrict__ cw)
{
    const int t = threadIdx.x;
    const int b = blockIdx.x;
    const int q0 = blockIdx.y * 128;
    const int k0 = blockIdx.z * 1024 + t * 4;
    const ushort_t* Pb = P + ((size_t)b * SS + q0) * SS;
    const float* lb = l + (size_t)b * SS + q0;
    float a0 = 0.f, a1 = 0.f, a2 = 0.f, a3 = 0.f;
    for (int q = 0; q < 128; q++) {
        float rl = 1.0f / lb[q];
        uint2 pp = *reinterpret_cast<const uint2*>(&Pb[(size_t)q * SS + k0]);
        a0 = fmaf(bf2f((ushort_t)(pp.x & 0xFFFF)), rl, a0);
        a1 = fmaf(bf2f((ushort_t)(pp.x >> 16)), rl, a1);
        a2 = fmaf(bf2f((ushort_t)(pp.y & 0xFFFF)), rl, a2);
        a3 = fmaf(bf2f((ushort_t)(pp.y >> 16)), rl, a3);
    }
    atomicAdd(&cw[(size_t)b * SS + k0], a0);
    atomicAdd(&cw[(size_t)b * SS + k0 + 1], a1);
    atomicAdd(&cw[(size_t)b * SS + k0 + 2], a2);
    atomicAdd(&cw[(size_t)b * SS + k0 + 3], a3);
}

// ---------- k4: out = (xsum + sum_k cw*v) / S ----------
__global__ __launch_bounds__(256) void k4_out(
    const float* __restrict__ xsum, const ushort_t* __restrict__ v,
    const float* __restrict__ cwv, float* __restrict__ out)
{
    const int b = blockIdx.x, c = blockIdx.y;
    const int t = threadIdx.x;
    const int srow0 = c * (SS / 16);
    const ushort_t* vb = v + ((size_t)b * SS + srow0) * DDIM;
    const float* cwb   = cwv + (size_t)b * SS + srow0;
    float a0 = (c == 0) ? xsum[b * DDIM + t]       : 0.f;
    float a1 = (c == 0) ? xsum[b * DDIM + t + 256] : 0.f;
    for (int r = 0; r < SS / 16; r++) {
        float w = cwb[r];
        a0 += w * bf2f(vb[(size_t)r * DDIM + t]);
        a1 += w * bf2f(vb[(size_t)r * DDIM + t + 256]);
    }
    atomicAdd(&out[b * DDIM + t],       a0 * (1.0f / SS));
    atomicAdd(&out[b * DDIM + t + 256], a1 * (1.0f / SS));
}

extern "C" void kernel_launch(void* const* d_in, const int* in_sizes, int n_in,
                              void* d_out, int out_size, void* d_ws, size_t ws_size,
                              hipStream_t stream)
{
    const float* x      = (const float*)d_in[0];
    const float* conv_w = (const float*)d_in[1];
    const float* conv_b = (const float*)d_in[2];
    const float* pre_g  = (const float*)d_in[3];
    const float* q_g    = (const float*)d_in[4];
    const float* k_g    = (const float*)d_in[5];
    const float* Wq     = (const float*)d_in[6];
    const float* Wk     = (const float*)d_in[7];
    const float* Wv     = (const float*)d_in[8];
    float* out          = (float*)d_out;

    const size_t NTOK  = (size_t)BB * SS * DDIM;
    const size_t NTOKG = (size_t)BB * SSG * DDIM;
    char* p = (char*)d_ws;
    ushort_t* xbf = (ushort_t*)p; p += NTOKG * 2;
    ushort_t* ybf = (ushort_t*)p; p += NTOK * 2;
    /* xn (unused since k1n fused into k1c) */ p += NTOK * 2;
    char* padreg = p;             p += NTOK * 2;   // rope table; dead once k2a aliases P
    ushort_t* qio = (ushort_t*)p; p += NTOK * 2;
    ushort_t* kio = (ushort_t*)p; p += NTOK * 2;
    ushort_t* vb  = (ushort_t*)p; p += NTOK * 2;
    ushort_t* wcat = (ushort_t*)p; p += (size_t)DDIM * KC * 2;
    ushort_t* wqkv = (ushort_t*)p; p += (size_t)KC * DDIM * 2;
    float* rs   = (float*)p; p += (size_t)BB * SS * 4;
    float* rq   = (float*)p; p += (size_t)BB * SS * 4;
    float* rk   = (float*)p; p += (size_t)BB * SS * 4;
    float* lbuf = (float*)p; p += (size_t)BB * SS * 4;
    float* cwb  = (float*)p; p += (size_t)BB * SS * 4;
    float* xsum = (float*)p; p += (size_t)BB * DDIM * 4;

    ushort_t* Pbuf = xbf;            // 67.1 MB aliased region (xbf/ybf/xn/pad dead by k2a)
    float* rope = (float*)padreg;    // 4 MB rope table in the dead pad region

    (void)hipMemsetAsync(d_out, 0, (size_t)out_size * sizeof(float), stream);
    (void)hipMemsetAsync(rs, 0, ((size_t)BB * SS * 5 + (size_t)BB * DDIM) * sizeof(float), stream);

    kprep<<<dim3(DDIM * KC / 256 + BB * SS / 16), 256, 0, stream>>>(
        x, conv_w, Wq, Wk, Wv, pre_g, xbf, xsum, wcat, wqkv, rope);
    k1b_conv<<<dim3(BB, SS / 128, 4), 256, 0, stream>>>(xbf, wcat, conv_b, ybf, rs);
    k1c_qkv<<<dim3(BB, SS / 128, 12), 256, 0, stream>>>(ybf, rs, wqkv, qio, kio, vb, rq, rk);
    k1d_rope<<<dim3(BB, SS / 8), 256, 0, stream>>>(qio, kio, rq, rk, q_g, k_g, rope);
    k2a_rowsum<<<dim3(BB, SS / 128, SS / 128), 256, 0, stream>>>(qio, kio, Pbuf, lbuf);
    k2c_colred<<<dim3(BB, SS / 128, SS / 1024), 256, 0, stream>>>(Pbuf, lbuf, cwb);
    k4_out<<<dim3(BB, 16), 256, 0, stream>>>(xsum, vb, cwb, out);
}

// Round 10
// 266.561 us; speedup vs baseline: 1.1391x; 1.1391x over previous
//
#include <hip/hip_runtime.h>
#include <math.h>

#define BB 8
#define SS 2048
#define SSG 2050          // SS + 2 guard rows per batch for conv halo
#define DDIM 512
#define KC 1536
#define EPSV 1e-6f
#define SCALE 0.044194173824159216f   // 1/sqrt(512)

typedef unsigned short ushort_t;
using short8 = __attribute__((ext_vector_type(8))) short;
using f32x4  = __attribute__((ext_vector_type(4))) float;

__device__ inline unsigned short f2bf(float f) {
    union { float f; unsigned int u; } v; v.f = f;
    unsigned int r = v.u + 0x7FFFu + ((v.u >> 16) & 1u);   // RNE
    return (unsigned short)(r >> 16);
}
__device__ inline unsigned int packbf(float a, float b) {
    return (unsigned int)f2bf(a) | ((unsigned int)f2bf(b) << 16);
}
__device__ inline float bf2f(unsigned short s) {
    union { unsigned int u; float f; } v; v.u = ((unsigned int)s) << 16; return v.f;
}

// async global->LDS, 16B/lane; LDS dest is wave-uniform base + lane*16 (linear).
__device__ inline void gload16(const ushort_t* g, ushort_t* l) {
    __builtin_amdgcn_global_load_lds(
        (__attribute__((address_space(1))) const void*)g,
        (__attribute__((address_space(3))) void*)l, 16, 0, 0);
}

// swizzled fragment read from a linear [128][64] bf16 tile (128B rows).
// logical 16B chunk c (0..7) of row -> stored at chunk c ^ (row&7); source applies
// the same XOR (rule #21). R1 measured: SQ_LDS_BANK_CONFLICT == 0 with this pair.
__device__ inline short8 ldswz(const ushort_t* s, int row, int c) {
    return *reinterpret_cast<const short8*>(&s[(row << 6) + ((c ^ (row & 7)) << 3)]);
}

// ---------- kx: x fp32 -> bf16 (guarded layout), plus xsum[b][d] = sum_s x ----------
__global__ __launch_bounds__(256) void kx_cast(const float* __restrict__ x,
                                               ushort_t* __restrict__ xbf,
                                               float* __restrict__ xsum)
{
    const int t = threadIdx.x;
    const int b = blockIdx.x;
    const int r0 = blockIdx.y * 16;
    const int c0 = 2 * t;
    if (blockIdx.y == 0) {   // zero guard rows (row -1 and row SS of this batch)
        *reinterpret_cast<unsigned int*>(&xbf[((size_t)b * SSG) * DDIM + c0]) = 0u;
        *reinterpret_cast<unsigned int*>(&xbf[((size_t)b * SSG + SS + 1) * DDIM + c0]) = 0u;
    }
    float s0 = 0.f, s1 = 0.f;
    for (int r = 0; r < 16; r++) {
        size_t srow = (size_t)b * SS + r0 + r;
        size_t drow = (size_t)b * SSG + 1 + r0 + r;
        float2 v = *reinterpret_cast<const float2*>(&x[srow * DDIM + c0]);
        s0 += v.x; s1 += v.y;
        *reinterpret_cast<unsigned int*>(&xbf[drow * DDIM + c0]) = packbf(v.x, v.y);
    }
    atomicAdd(&xsum[b * DDIM + c0], s0);
    atomicAdd(&xsum[b * DDIM + c0 + 1], s1);
}

// ---------- k0: weights -> bf16 (pre_g folded into wqkv cols) + rope table ----------
__global__ __launch_bounds__(256) void k0_prep(
    const float* __restrict__ conv_w, const float* __restrict__ Wq,
    const float* __restrict__ Wk, const float* __restrict__ Wv,
    const float* __restrict__ pre_g,
    ushort_t* __restrict__ wcat, ushort_t* __restrict__ wqkv,
    float* __restrict__ rope)
{
    int idx = blockIdx.x * 256 + threadIdx.x;   // < 512*1536
    {
        int o = idx / KC, kk = idx - o * KC;
        int t = kk >> 9, i = kk & 511;
        wcat[idx] = f2bf(conv_w[(size_t)o * KC + i * 3 + t]);
    }
    {
        int n = idx >> 9, d = idx & 511;
        const float* src = (n < 512) ? &Wq[(size_t)n * DDIM + d]
                         : (n < 1024) ? &Wk[(size_t)(n - 512) * DDIM + d]
                         : &Wv[(size_t)(n - 1024) * DDIM + d];
        wqkv[idx] = f2bf(*src * pre_g[d]);      // fold pre_g into W columns
    }
    // rope table: blocks 0..SS/8-1 additionally fill 8 rows each
    if (blockIdx.x < SS / 8) {
        const int t = threadIdx.x;
        const int r0 = blockIdx.x * 8;
        const float invf = (float)pow(10000.0, -(double)(2 * t) / (double)DDIM);
        for (int r = 0; r < 8; r++) {
            int srow = r0 + r;
            float sn, cs;
            sincosf((float)srow * invf, &sn, &cs);
            *reinterpret_cast<float2*>(&rope[((size_t)srow << 9) + 2 * t]) = make_float2(cs, sn);
        }
    }
}

// ---------- shared GEMM inner compute (one BK=64 tile) — R1-verified ----------
#define COMPUTE_TILE(Acur, Bcur) do { \
    _Pragma("unroll") \
    for (int half = 0; half < 2; half++) { \
        const int cb = (half << 2) | lq; \
        short8 af0 = ldswz(Acur, wm * 64 +  0 + lm, cb); \
        short8 af1 = ldswz(Acur, wm * 64 + 16 + lm, cb); \
        short8 af2 = ldswz(Acur, wm * 64 + 32 + lm, cb); \
        short8 af3 = ldswz(Acur, wm * 64 + 48 + lm, cb); \
        _Pragma("unroll") \
        for (int nt = 0; nt < 4; nt++) { \
            short8 bfv = ldswz(Bcur, wn * 64 + nt * 16 + lm, cb); \
            acc[0][nt] = __builtin_amdgcn_mfma_f32_16x16x32_bf16(af0, bfv, acc[0][nt], 0, 0, 0); \
            acc[1][nt] = __builtin_amdgcn_mfma_f32_16x16x32_bf16(af1, bfv, acc[1][nt], 0, 0, 0); \
            acc[2][nt] = __builtin_amdgcn_mfma_f32_16x16x32_bf16(af2, bfv, acc[2][nt], 0, 0, 0); \
            acc[3][nt] = __builtin_amdgcn_mfma_f32_16x16x32_bf16(af3, bfv, acc[3][nt], 0, 0, 0); \
        } \
    } } while (0)

// ---------- k1b: conv GEMM, BK=64, R1 loop; batch-affine grid ----------
__global__ __launch_bounds__(256) void k1b_conv(
    const ushort_t* __restrict__ xbf, const ushort_t* __restrict__ wcat,
    const float* __restrict__ conv_b, ushort_t* __restrict__ ybf, float* __restrict__ rs)
{
    __shared__ alignas(16) ushort_t As[128 * 64];
    __shared__ alignas(16) ushort_t Bs[128 * 64];
    const int t = threadIdx.x;
    const int lane = t & 63, w = t >> 6;
    const int lm = lane & 15, lq = lane >> 4;
    const int wm = w >> 1, wn = w & 1;
    const int lr = lane >> 3;                 // row within 8-row load block
    const int lc = ((lane & 7) ^ lr) << 3;    // source-side XOR-swizzled chunk
    const int b  = blockIdx.x;
    const int s0 = blockIdx.y * 128;
    const int n0 = blockIdx.z * 128;
    const ushort_t* Ag = xbf + (size_t)b * SSG * DDIM;   // guard base: g-row = true + 1
    const ushort_t* Bg = wcat + (size_t)n0 * KC;

    const ushort_t* pa[4]; const ushort_t* pb[4];
    int la[4];
    #pragma unroll
    for (int i = 0; i < 4; i++) {
        const int tr = (w * 4 + i) * 8 + lr;
        pa[i] = &Ag[(size_t)(s0 + tr) * DDIM + lc];
        pb[i] = &Bg[(size_t)tr * KC + lc];
        la[i] = (w * 4 + i) * 512;
    }

    f32x4 acc[4][4];
    #pragma unroll
    for (int i = 0; i < 4; i++)
        #pragma unroll
        for (int j = 0; j < 4; j++) acc[i][j] = (f32x4){0.f, 0.f, 0.f, 0.f};

    for (int dc = 0; dc < 24; dc++) {
        __syncthreads();                       // prev tile reads done
        const int koff = dc * 64;              // tap*512 + kblk*64 == dc*64 (uniform)
        #pragma unroll
        for (int i = 0; i < 4; i++) {
            gload16(pa[i] + koff, &As[la[i]]);
            gload16(pb[i] + koff, &Bs[la[i]]);
        }
        __syncthreads();                       // vmcnt(0) drain -> tile ready
        COMPUTE_TILE(As, Bs);
    }

    const int rbase = s0 + wm * 64;
    const int cbase = n0 + wn * 64;
    ushort_t* yb = ybf + (size_t)b * SS * DDIM;
    float* rsb = rs + (size_t)b * SS;
    float bias[4];
    #pragma unroll
    for (int nt = 0; nt < 4; nt++) bias[nt] = conv_b[cbase + nt * 16 + lm];
    #pragma unroll
    for (int mt = 0; mt < 4; mt++) {
        float pr[4] = {0.f, 0.f, 0.f, 0.f};
        #pragma unroll
        for (int nt = 0; nt < 4; nt++) {
            #pragma unroll
            for (int r = 0; r < 4; r++) {
                float val = acc[mt][nt][r] + bias[nt];
                yb[(size_t)(rbase + mt * 16 + lq * 4 + r) * DDIM + cbase + nt * 16 + lm] = f2bf(val);
                pr[r] = fmaf(val, val, pr[r]);
            }
        }
        #pragma unroll
        for (int r = 0; r < 4; r++) {
            float p = pr[r];
            p += __shfl_xor(p, 1, 64); p += __shfl_xor(p, 2, 64);
            p += __shfl_xor(p, 4, 64); p += __shfl_xor(p, 8, 64);
            if (lm == 0) atomicAdd(&rsb[rbase + mt * 16 + lq * 4 + r], p);
        }
    }
}

// ---------- k1c: QKV GEMM from ybf (pre_g folded into W), inv[s] applied in epilogue ----------
__global__ __launch_bounds__(256) void k1c_qkv(
    const ushort_t* __restrict__ ybf, const float* __restrict__ rs,
    const ushort_t* __restrict__ wqkv,
    ushort_t* __restrict__ qraw, ushort_t* __restrict__ kraw, ushort_t* __restrict__ vb,
    float* __restrict__ rq, float* __restrict__ rk)
{
    __shared__ alignas(16) ushort_t As[128 * 64];
    __shared__ alignas(16) ushort_t Bs[128 * 64];
    const int t = threadIdx.x;
    const int lane = t & 63, w = t >> 6;
    const int lm = lane & 15, lq = lane >> 4;
    const int wm = w >> 1, wn = w & 1;
    const int lr = lane >> 3;
    const int lc = ((lane & 7) ^ lr) << 3;
    const int b  = blockIdx.x;
    const int s0 = blockIdx.y * 128;
    const int nt9 = blockIdx.z;                 // 0..11: which*4 + coltile
    const int n0 = nt9 * 128;
    const ushort_t* Ag = ybf + ((size_t)b * SS + s0) * DDIM;
    const ushort_t* Bg = wqkv + (size_t)n0 * DDIM;

    const ushort_t* pa[4]; const ushort_t* pb[4];
    int la[4];
    #pragma unroll
    for (int i = 0; i < 4; i++) {
        const int tr = (w * 4 + i) * 8 + lr;
        pa[i] = &Ag[(size_t)tr * DDIM + lc];
        pb[i] = &Bg[(size_t)tr * DDIM + lc];
        la[i] = (w * 4 + i) * 512;
    }

    f32x4 acc[4][4];
    #pragma unroll
    for (int i = 0; i < 4; i++)
        #pragma unroll
        for (int j = 0; j < 4; j++) acc[i][j] = (f32x4){0.f, 0.f, 0.f, 0.f};

    for (int dc = 0; dc < 8; dc++) {
        __syncthreads();
        const int koff = dc * 64;
        #pragma unroll
        for (int i = 0; i < 4; i++) {
            gload16(pa[i] + koff, &As[la[i]]);
            gload16(pb[i] + koff, &Bs[la[i]]);
        }
        __syncthreads();
        COMPUTE_TILE(As, Bs);
    }

    const int which = nt9 >> 2;              // 0=q 1=k 2=v
    const int rbase = s0 + wm * 64;
    const int cbase = ((nt9 & 3) * 128) + wn * 64;
    const float* rsb = rs + (size_t)b * SS;
    float inv[4][4];                          // per-row rmsnorm inverse (pre-norm)
    #pragma unroll
    for (int mt = 0; mt < 4; mt++)
        #pragma unroll
        for (int r = 0; r < 4; r++)
            inv[mt][r] = rsqrtf(rsb[rbase + mt * 16 + lq * 4 + r] * (1.0f / DDIM) + EPSV);

    if (which == 2) {
        ushort_t* vbb = vb + (size_t)b * SS * DDIM;
        #pragma unroll
        for (int mt = 0; mt < 4; mt++)
            #pragma unroll
            for (int nt = 0; nt < 4; nt++)
                #pragma unroll
                for (int r = 0; r < 4; r++)
                    vbb[(size_t)(rbase + mt * 16 + lq * 4 + r) * DDIM + cbase + nt * 16 + lm] =
                        f2bf(acc[mt][nt][r] * inv[mt][r]);
    } else {
        ushort_t* db2 = (which ? kraw : qraw) + (size_t)b * SS * DDIM;
        float* rb = (which ? rk : rq) + (size_t)b * SS;
        #pragma unroll
        for (int mt = 0; mt < 4; mt++) {
            float pr[4] = {0.f, 0.f, 0.f, 0.f};
            #pragma unroll
            for (int nt = 0; nt < 4; nt++) {
                #pragma unroll
                for (int r = 0; r < 4; r++) {
                    float val = acc[mt][nt][r] * inv[mt][r];
                    db2[(size_t)(rbase + mt * 16 + lq * 4 + r) * DDIM + cbase + nt * 16 + lm] = f2bf(val);
                    pr[r] = fmaf(val, val, pr[r]);
                }
            }
            #pragma unroll
            for (int r = 0; r < 4; r++) {
                float p = pr[r];
                p += __shfl_xor(p, 1, 64); p += __shfl_xor(p, 2, 64);
                p += __shfl_xor(p, 4, 64); p += __shfl_xor(p, 8, 64);
                if (lm == 0) atomicAdd(&rb[rbase + mt * 16 + lq * 4 + r], p);
            }
        }
    }
}

// ---------- k1d: rmsnorm(q,k) + rope (table), in-place; vectorized 8 bf16/thread ----------
__global__ __launch_bounds__(256) void k1d_rope(
    ushort_t* q_io, ushort_t* k_io,
    const float* __restrict__ rq, const float* __restrict__ rk,
    const float* __restrict__ q_g, const float* __restrict__ k_g,
    const float* __restrict__ rope)
{
    const int t = threadIdx.x;
    const int b = blockIdx.x;
    const int r0 = blockIdx.y * 8;
    const int tr = t >> 6;                    // 0..3
    const int c0 = (t & 63) * 8;              // 8 cols per thread
    float4 qg0 = *reinterpret_cast<const float4*>(&q_g[c0]);
    float4 qg1 = *reinterpret_cast<const float4*>(&q_g[c0 + 4]);
    float4 kg0 = *reinterpret_cast<const float4*>(&k_g[c0]);
    float4 kg1 = *reinterpret_cast<const float4*>(&k_g[c0 + 4]);
    const float qg[8] = {qg0.x, qg0.y, qg0.z, qg0.w, qg1.x, qg1.y, qg1.z, qg1.w};
    const float kg[8] = {kg0.x, kg0.y, kg0.z, kg0.w, kg1.x, kg1.y, kg1.z, kg1.w};
    #pragma unroll
    for (int r = 0; r < 2; r++) {
        const int srow = r0 + tr + 4 * r;
        const size_t rowi = (size_t)b * SS + srow;
        const float iq = rsqrtf(rq[rowi] * (1.0f / DDIM) + EPSV);
        const float ik = rsqrtf(rk[rowi] * (1.0f / DDIM) + EPSV);
        const size_t off = rowi * DDIM + c0;
        uint4 qv = *reinterpret_cast<const uint4*>(&q_io[off]);
        uint4 kv = *reinterpret_cast<const uint4*>(&k_io[off]);
        float4 cs0 = *reinterpret_cast<const float4*>(&rope[((size_t)srow << 9) + c0]);
        float4 cs1 = *reinterpret_cast<const float4*>(&rope[((size_t)srow << 9) + c0 + 4]);
        const float cs[4] = {cs0.x, cs0.z, cs1.x, cs1.z};
        const float sn[4] = {cs0.y, cs0.w, cs1.y, cs1.w};
        unsigned int qw[4] = {qv.x, qv.y, qv.z, qv.w};
        unsigned int kw[4] = {kv.x, kv.y, kv.z, kv.w};
        uint4 qo, ko;
        unsigned int* qop = &qo.x; unsigned int* kop = &ko.x;
        #pragma unroll
        for (int j = 0; j < 4; j++) {
            float qa = bf2f((ushort_t)(qw[j] & 0xFFFF)) * iq * qg[2 * j];
            float qb = bf2f((ushort_t)(qw[j] >> 16))    * iq * qg[2 * j + 1];
            float ka = bf2f((ushort_t)(kw[j] & 0xFFFF)) * ik * kg[2 * j];
            float kb = bf2f((ushort_t)(kw[j] >> 16))    * ik * kg[2 * j + 1];
            qop[j] = packbf(qa * cs[j] - qb * sn[j], qa * sn[j] + qb * cs[j]);
            kop[j] = packbf(ka * cs[j] - kb * sn[j], ka * sn[j] + kb * cs[j]);
        }
        *reinterpret_cast<uint4*>(&q_io[off]) = qo;
        *reinterpret_cast<uint4*>(&k_io[off]) = ko;
    }
}

// ---------- k2a: scores GEMM (R1 loop, unchanged) -> P + row sums l ----------
// Grid (BB, qt, kt): linear id % 8 == batch -> XCD-affine; per-batch Q+K (4MB) ~fits one L2.
__global__ __launch_bounds__(256) void k2a_rowsum(
    const ushort_t* __restrict__ qb, const ushort_t* __restrict__ kb,
    ushort_t* __restrict__ P, float* __restrict__ l)
{
    __shared__ alignas(16) ushort_t As[128 * 64];
    __shared__ alignas(16) ushort_t Bs[128 * 64];
    const int t = threadIdx.x;
    const int lane = t & 63, w = t >> 6;
    const int lm = lane & 15, lq = lane >> 4;
    const int wm = w >> 1, wn = w & 1;
    const int lr = lane >> 3;
    const int lc = ((lane & 7) ^ lr) << 3;
    const int b  = blockIdx.x;
    const int qt = blockIdx.y;
    const int kt = blockIdx.z;
    const ushort_t* Ag = qb + ((size_t)b * SS + qt * 128) * DDIM;
    const ushort_t* Bg = kb + ((size_t)b * SS + kt * 128) * DDIM;

    const ushort_t* pa[4]; const ushort_t* pb[4];
    int la[4];
    #pragma unroll
    for (int i = 0; i < 4; i++) {
        const int tr = (w * 4 + i) * 8 + lr;
        pa[i] = &Ag[(size_t)tr * DDIM + lc];
        pb[i] = &Bg[(size_t)tr * DDIM + lc];
        la[i] = (w * 4 + i) * 512;
    }

    f32x4 acc[4][4];
    #pragma unroll
    for (int i = 0; i < 4; i++)
        #pragma unroll
        for (int j = 0; j < 4; j++) acc[i][j] = (f32x4){0.f, 0.f, 0.f, 0.f};

    for (int dc = 0; dc < 8; dc++) {
        __syncthreads();
        const int koff = dc * 64;
        #pragma unroll
        for (int i = 0; i < 4; i++) {
            gload16(pa[i] + koff, &As[la[i]]);
            gload16(pb[i] + koff, &Bs[la[i]]);
        }
        __syncthreads();
        COMPUTE_TILE(As, Bs);
    }

    const int rbase = qt * 128 + wm * 64;
    const int cbase = kt * 128 + wn * 64;
    ushort_t* Pb = P + (size_t)b * SS * SS;
    float* lrow = l + (size_t)b * SS;
    #pragma unroll
    for (int mt = 0; mt < 4; mt++) {
        #pragma unroll
        for (int r = 0; r < 4; r++) {
            const int row = rbase + mt * 16 + lq * 4 + r;
            float rowp = 0.f;
            #pragma unroll
            for (int nt = 0; nt < 4; nt++) {
                float e = __expf(acc[mt][nt][r] * SCALE);
                Pb[(size_t)row * SS + cbase + nt * 16 + lm] = f2bf(e);
                rowp += e;
            }
            float p = rowp;
            p += __shfl_xor(p, 1, 64); p += __shfl_xor(p, 2, 64);
            p += __shfl_xor(p, 4, 64); p += __shfl_xor(p, 8, 64);
            if (lm == 0) atomicAdd(&lrow[row], p);
        }
    }
}

// ---------- k2c: cw[k] = sum_q P[q][k] / l[q] ----------
__global__ __launch_bounds__(256) void k2c_colred(
    const ushort_t* __restrict__ P, const float* __restrict__ l,
    float* __restrict__ cw)
{
    const int t = threadIdx.x;
    const int b = blockIdx.x;
    const int q0 = blockIdx.y * 128;
    const int k0 = blockIdx.z * 1024 + t * 4;
    const ushort_t* Pb = P + ((size_t)b * SS + q0) * SS;
    const float* lb = l + (size_t)b * SS + q0;
    float a0 = 0.f, a1 = 0.f, a2 = 0.f, a3 = 0.f;
    for (int q = 0; q < 128; q++) {
        float rl = 1.0f / lb[q];
        uint2 pp = *reinterpret_cast<const uint2*>(&Pb[(size_t)q * SS + k0]);
        a0 = fmaf(bf2f((ushort_t)(pp.x & 0xFFFF)), rl, a0);
        a1 = fmaf(bf2f((ushort_t)(pp.x >> 16)), rl, a1);
        a2 = fmaf(bf2f((ushort_t)(pp.y & 0xFFFF)), rl, a2);
        a3 = fmaf(bf2f((ushort_t)(pp.y >> 16)), rl, a3);
    }
    atomicAdd(&cw[(size_t)b * SS + k0], a0);
    atomicAdd(&cw[(size_t)b * SS + k0 + 1], a1);
    atomicAdd(&cw[(size_t)b * SS + k0 + 2], a2);
    atomicAdd(&cw[(size_t)b * SS + k0 + 3], a3);
}

// ---------- k4: out = (xsum + sum_k cw*v) / S ----------
__global__ __launch_bounds__(256) void k4_out(
    const float* __restrict__ xsum, const ushort_t* __restrict__ v,
    const float* __restrict__ cwv, float* __restrict__ out)
{
    const int b = blockIdx.x, c = blockIdx.y;
    const int t = threadIdx.x;
    const int srow0 = c * (SS / 16);
    const ushort_t* vb = v + ((size_t)b * SS + srow0) * DDIM;
    const float* cwb   = cwv + (size_t)b * SS + srow0;
    float a0 = (c == 0) ? xsum[b * DDIM + t]       : 0.f;
    float a1 = (c == 0) ? xsum[b * DDIM + t + 256] : 0.f;
    for (int r = 0; r < SS / 16; r++) {
        float w = cwb[r];
        a0 += w * bf2f(vb[(size_t)r * DDIM + t]);
        a1 += w * bf2f(vb[(size_t)r * DDIM + t + 256]);
    }
    atomicAdd(&out[b * DDIM + t],       a0 * (1.0f / SS));
    atomicAdd(&out[b * DDIM + t + 256], a1 * (1.0f / SS));
}

extern "C" void kernel_launch(void* const* d_in, const int* in_sizes, int n_in,
                              void* d_out, int out_size, void* d_ws, size_t ws_size,
                              hipStream_t stream)
{
    const float* x      = (const float*)d_in[0];
    const float* conv_w = (const float*)d_in[1];
    const float* conv_b = (const float*)d_in[2];
    const float* pre_g  = (const float*)d_in[3];
    const float* q_g    = (const float*)d_in[4];
    const float* k_g    = (const float*)d_in[5];
    const float* Wq     = (const float*)d_in[6];
    const float* Wk     = (const float*)d_in[7];
    const float* Wv     = (const float*)d_in[8];
    float* out          = (float*)d_out;

    const size_t NTOK  = (size_t)BB * SS * DDIM;
    const size_t NTOKG = (size_t)BB * SSG * DDIM;
    char* p = (char*)d_ws;
    ushort_t* xbf = (ushort_t*)p; p += NTOKG * 2;
    ushort_t* ybf = (ushort_t*)p; p += NTOK * 2;
    /* xn (unused since k1n fused into k1c) */ p += NTOK * 2;
    char* padreg = p;             p += NTOK * 2;   // rope table; dead once k2a aliases P
    ushort_t* qio = (ushort_t*)p; p += NTOK * 2;
    ushort_t* kio = (ushort_t*)p; p += NTOK * 2;
    ushort_t* vb  = (ushort_t*)p; p += NTOK * 2;
    ushort_t* wcat = (ushort_t*)p; p += (size_t)DDIM * KC * 2;
    ushort_t* wqkv = (ushort_t*)p; p += (size_t)KC * DDIM * 2;
    float* rs   = (float*)p; p += (size_t)BB * SS * 4;
    float* rq   = (float*)p; p += (size_t)BB * SS * 4;
    float* rk   = (float*)p; p += (size_t)BB * SS * 4;
    float* lbuf = (float*)p; p += (size_t)BB * SS * 4;
    float* cwb  = (float*)p; p += (size_t)BB * SS * 4;
    float* xsum = (float*)p; p += (size_t)BB * DDIM * 4;

    ushort_t* Pbuf = xbf;            // 67.1 MB aliased region (xbf/ybf/xn/pad dead by k2a)
    float* rope = (float*)padreg;    // 4 MB rope table in the dead pad region

    (void)hipMemsetAsync(d_out, 0, (size_t)out_size * sizeof(float), stream);
    (void)hipMemsetAsync(rs, 0, ((size_t)BB * SS * 5 + (size_t)BB * DDIM) * sizeof(float), stream);

    kx_cast<<<dim3(BB, SS / 16), 256, 0, stream>>>(x, xbf, xsum);
    k0_prep<<<dim3(DDIM * KC / 256), 256, 0, stream>>>(conv_w, Wq, Wk, Wv, pre_g, wcat, wqkv, rope);
    k1b_conv<<<dim3(BB, SS / 128, 4), 256, 0, stream>>>(xbf, wcat, conv_b, ybf, rs);
    k1c_qkv<<<dim3(BB, SS / 128, 12), 256, 0, stream>>>(ybf, rs, wqkv, qio, kio, vb, rq, rk);
    k1d_rope<<<dim3(BB, SS / 8), 256, 0, stream>>>(qio, kio, rq, rk, q_g, k_g, rope);
    k2a_rowsum<<<dim3(BB, SS / 128, SS / 128), 256, 0, stream>>>(qio, kio, Pbuf, lbuf);
    k2c_colred<<<dim3(BB, SS / 128, SS / 1024), 256, 0, stream>>>(Pbuf, lbuf, cwb);
    k4_out<<<dim3(BB, 16), 256, 0, stream>>>(xsum, vb, cwb, out);
}